// Round 8
// baseline (585.698 us; speedup 1.0000x reference)
//
#include <hip/hip_runtime.h>
#include <utility>

#define HH 20

// Raw v_rcp_f32 (~1 ulp); threshold 1.9e-3.
__device__ __forceinline__ float fast_rcp(float x) { return __builtin_amdgcn_rcpf(x); }
__device__ __forceinline__ float fsigmoid(float x) { return fast_rcp(1.0f + __expf(-x)); }
__device__ __forceinline__ float ftanh(float x) {
    float e = __expf(2.0f * x);
    return 1.0f - 2.0f * fast_rcp(e + 1.0f);
}
// DPP quad_perm [1,0,3,2]: swap values across adjacent lane pairs (VALU pipe).
__device__ __forceinline__ float pswap(float v) {
    return __int_as_float(__builtin_amdgcn_mov_dpp(__float_as_int(v), 0xB1, 0xF, 0xF, true));
}

// ---- LDS weight arena with per-gate bank pads -------------------------------
// Each gate block is 20*IN + 4 floats. R7 evidence: unpadded layout put the
// wave's two concurrent row addresses (s=0: gates i/f, s=1: o/g) on the SAME
// bank quad (delta % 32 == 0 for IN=4/16/20) -> 1.05e7 conflict cycles. With
// +4 pads the deltas mod 32 are {12,28,4,20} -> disjoint quads, conflict-free.
constexpr int BLK16 = 20 * 16 + 4;   // 324
constexpr int BLK20 = 20 * 20 + 4;   // 404
constexpr int BLK4  = 20 * 4 + 4;    // 84

constexpr int W_Wih1_0 = 0;                       // 4*324 = 1296
constexpr int W_Whh1_0 = W_Wih1_0 + 4 * BLK16;    // 1296: 1616
constexpr int W_b1_0   = W_Whh1_0 + 4 * BLK20;    // 2912: 80
constexpr int W_Wih1_1 = W_b1_0 + 80;             // 2992: 1616
constexpr int W_Whh1_1 = W_Wih1_1 + 4 * BLK20;    // 4608: 1616
constexpr int W_b1_1   = W_Whh1_1 + 4 * BLK20;    // 6224: 80
constexpr int W_Wih2_0 = W_b1_1 + 80;             // 6304: 336
constexpr int W_Whh2_0 = W_Wih2_0 + 4 * BLK4;     // 6640: 1616
constexpr int W_b2_0   = W_Whh2_0 + 4 * BLK20;    // 8256: 80
constexpr int W_Wih2_1 = W_b2_0 + 80;             // 8336: 1616
constexpr int W_Whh2_1 = W_Wih2_1 + 4 * BLK20;    // 9952: 1616
constexpr int W_b2_1   = W_Whh2_1 + 4 * BLK20;    // 11568: 80
constexpr int W_fW1    = W_b2_1 + 80;             // 11648: 200
constexpr int W_fb1    = W_fW1 + 200;             // 11848: 10
constexpr int W_fW2    = W_fb1 + 12;              // 11860: 100
constexpr int W_fb2    = W_fW2 + 100;             // 11960: 10
constexpr int W_fW3    = W_fb2 + 12;              // 11972: 10
constexpr int W_fb3    = W_fW3 + 10;              // 11982: 1
constexpr int LDS_TOT  = W_fb3 + 2;               // 11984 floats = 47.9 KB

// One float4 weight chunk feeding both elements (8 FMA per ds_read_b128).
// Accumulators are (own, oth): own = this lane's element, oth = partner's.
template <int IN, size_t U, size_t K>
__device__ __forceinline__ void row2_k(const float (&sm)[LDS_TOT], int rb,
                                       const float (&vo)[IN], const float (&vt)[IN],
                                       float& ao, float& at) {
    float4 w = *(const float4*)&sm[rb + (int)(U * IN + 4 * K)];
    ao = fmaf(w.x, vo[4 * K + 0], ao); at = fmaf(w.x, vt[4 * K + 0], at);
    ao = fmaf(w.y, vo[4 * K + 1], ao); at = fmaf(w.y, vt[4 * K + 1], at);
    ao = fmaf(w.z, vo[4 * K + 2], ao); at = fmaf(w.z, vt[4 * K + 2], at);
    ao = fmaf(w.w, vo[4 * K + 3], ao); at = fmaf(w.w, vt[4 * K + 3], at);
}
template <int IN, size_t U, size_t... K>
__device__ __forceinline__ void row2(const float (&sm)[LDS_TOT], int rb,
                                     const float (&vo)[IN], const float (&vt)[IN],
                                     float& ao, float& at, std::index_sequence<K...>) {
    (row2_k<IN, U, K>(sm, rb, vo, vt, ao, at), ...);
}

// One LSTM unit, gate-split across a lane pair, own-element state only.
// s=0 lane: rows A=i, B=f (m=1 -> B act = sigma); s=1: A=o, B=g (m=2 -> tanh).
// After pswap of the 'oth' activations each lane holds all 4 gates for its OWN
// element; cn/hn computed only for own element (partner handles the other).
template <int IN, size_t U>
__device__ __forceinline__ void unit2(const float (&sm)[LDS_TOT], int s, float m, float mm1,
                                      int wihA, int wihB, int whhA, int whhB, int bA, int bB,
                                      const float (&x_own)[IN], const float (&x_oth)[IN],
                                      const float (&h_own)[HH], const float (&h_oth)[HH],
                                      float (&c_own)[HH], float (&hn)[HH]) {
    float aAo = sm[bA + (int)U], aAt = aAo;
    float aBo = sm[bB + (int)U], aBt = aBo;
    row2<IN, U>(sm, wihA, x_own, x_oth, aAo, aAt, std::make_index_sequence<IN / 4>{});
    row2<IN, U>(sm, wihB, x_own, x_oth, aBo, aBt, std::make_index_sequence<IN / 4>{});
    row2<HH, U>(sm, whhA, h_own, h_oth, aAo, aAt, std::make_index_sequence<HH / 4>{});
    row2<HH, U>(sm, whhB, h_own, h_oth, aBo, aBt, std::make_index_sequence<HH / 4>{});
    float Ao = fsigmoid(aAo), At = fsigmoid(aAt);
    float Bo = fmaf(m, fsigmoid(m * aBo), -mm1);
    float Bt = fmaf(m, fsigmoid(m * aBt), -mm1);
    float rA = pswap(At);   // s=0 receives sigma(o,own); s=1 receives sigma(i,own)
    float rB = pswap(Bt);   // s=0 receives tanh(g,own);  s=1 receives sigma(f,own)
    float sf = s ? rB : Bo;
    float si = s ? rA : Ao;
    float tg = s ? Bo : rB;
    float so = s ? Ao : rA;
    float cn = fmaf(sf, c_own[U], si * tg);
    c_own[U] = cn;
    hn[U] = so * ftanh(cn);
}

template <int WIH, int WHH, int BOFF, int IN, int BLK, size_t... U, size_t... K>
__device__ __forceinline__ void cell_impl(const float (&sm)[LDS_TOT], int wb, int s,
                                          float m, float mm1,
                                          const float (&x_own)[IN],
                                          float (&h_own)[HH], float (&c_own)[HH],
                                          std::index_sequence<U...>, std::index_sequence<K...>) {
    // materialize partner-element input & recurrent vectors (DPP, VALU pipe)
    float x_oth[IN], h_oth[HH];
    ((x_oth[K] = pswap(x_own[K])), ...);
    ((h_oth[U] = pswap(h_own[U])), ...);
    const int gA = s ? 3 : 0, gB = s ? 2 : 1;
    int wihA = wb + WIH + gA * BLK;
    int wihB = wb + WIH + gB * BLK;
    int whhA = wb + WHH + gA * BLK20;
    int whhB = wb + WHH + gB * BLK20;
    int bA = wb + BOFF + gA * 20;
    int bB = wb + BOFF + gB * 20;
    float hn[HH];
    (unit2<IN, U>(sm, s, m, mm1, wihA, wihB, whhA, whhB, bA, bB,
                  x_own, x_oth, h_own, h_oth, c_own, hn), ...);
    ((h_own[U] = hn[U]), ...);
}

template <int WIH, int WHH, int BOFF, int IN, int BLK>
__device__ __forceinline__ void cell(const float (&sm)[LDS_TOT], int wb, int s,
                                     float m, float mm1, const float (&x_own)[IN],
                                     float (&h_own)[HH], float (&c_own)[HH]) {
    cell_impl<WIH, WHH, BOFF, IN, BLK>(sm, wb, s, m, mm1, x_own, h_own, c_own,
                                       std::make_index_sequence<HH>{},
                                       std::make_index_sequence<IN>{});
}

template <int WOFF, size_t J, int LD, int NV, size_t... K>
__device__ __forceinline__ float mlp_dot(const float (&sm)[LDS_TOT], int wb, const float (&v)[NV],
                                         float a, std::index_sequence<K...>) {
    ((a = fmaf(sm[wb + WOFF + (int)(J * LD + K)], v[K], a)), ...);
    return a;
}
template <size_t... J>
__device__ __forceinline__ void mlp_l1(const float (&sm)[LDS_TOT], int wb,
                                       const float (&h)[HH], float (&z)[10], std::index_sequence<J...>) {
    ((z[J] = fmaxf(mlp_dot<W_fW1, J, HH>(sm, wb, h, sm[wb + W_fb1 + (int)J],
                                         std::make_index_sequence<HH>{}), 0.f)), ...);
}
template <size_t... J>
__device__ __forceinline__ void mlp_l2(const float (&sm)[LDS_TOT], int wb,
                                       const float (&z1)[10], float (&z2)[10], std::index_sequence<J...>) {
    ((z2[J] = fmaxf(mlp_dot<W_fW2, J, 10>(sm, wb, z1, sm[wb + W_fb2 + (int)J],
                                          std::make_index_sequence<10>{}), 0.f)), ...);
}

// launch_bounds(256,2): min 2 waves/EU -> 256-VGPR budget. Own-element state
// keeps peak pressure ~140, so even a conservative allocator choice holds
// without spills (R7: duplicated state @128 budget -> 340MB scratch writes).
__global__ void __launch_bounds__(256, 2) lstm_ar_kernel(
    const float* __restrict__ y_past, const float* __restrict__ x_past,
    const float* __restrict__ u_past, const float* __restrict__ s_past,
    const float* __restrict__ u_future,
    const float* __restrict__ Wih1_0, const float* __restrict__ Whh1_0, const float* __restrict__ b1_0,
    const float* __restrict__ Wih1_1, const float* __restrict__ Whh1_1, const float* __restrict__ b1_1,
    const float* __restrict__ Wih2_0, const float* __restrict__ Whh2_0, const float* __restrict__ b2_0,
    const float* __restrict__ Wih2_1, const float* __restrict__ Whh2_1, const float* __restrict__ b2_1,
    const float* __restrict__ fW1, const float* __restrict__ fb1,
    const float* __restrict__ fW2, const float* __restrict__ fb2,
    const float* __restrict__ fW3, const float* __restrict__ fb3,
    float* __restrict__ out, int B) {
    __shared__ __align__(16) float smem[LDS_TOT];
    const int tid = threadIdx.x;

    // ---- stage weights into LDS with per-gate +4 pads ----
    auto stage_w = [&](const float* src, int off, int IN) {
        const int gb = 20 * IN;
        for (int i = tid; i < 4 * gb; i += 256) {
            int g = i / gb;
            smem[off + g * (gb + 4) + (i - g * gb)] = src[i];
        }
    };
    auto stage = [&](const float* src, int off, int n) {
        for (int i = tid; i < n; i += 256) smem[off + i] = src[i];
    };
    stage_w(Wih1_0, W_Wih1_0, 16);
    stage_w(Whh1_0, W_Whh1_0, 20);
    stage(b1_0, W_b1_0, 80);
    stage_w(Wih1_1, W_Wih1_1, 20);
    stage_w(Whh1_1, W_Whh1_1, 20);
    stage(b1_1, W_b1_1, 80);
    stage_w(Wih2_0, W_Wih2_0, 4);
    stage_w(Whh2_0, W_Whh2_0, 20);
    stage(b2_0, W_b2_0, 80);
    stage_w(Wih2_1, W_Wih2_1, 20);
    stage_w(Whh2_1, W_Whh2_1, 20);
    stage(b2_1, W_b2_1, 80);
    stage(fW1, W_fW1, 200);
    stage(fb1, W_fb1, 10);
    stage(fW2, W_fW2, 100);
    stage(fb2, W_fb2, 10);
    stage(fW3, W_fW3, 10);
    stage(fb3, W_fb3, 1);
    __syncthreads();

    const int s = tid & 1;                    // gate half: 0 -> (i,f), 1 -> (o,g)
    const int e = blockIdx.x * 256 + tid;     // OWN element == global thread id
    if (e >= B) return;                       // never taken (B % 256 == 0)

    const float m   = s ? 2.0f : 1.0f;
    const float mm1 = m - 1.0f;

    // own-element state only: 80 registers
    float h0[HH], c0[HH], h1[HH], c1[HH];
    {
        auto zero = [&](auto... u) {
            ((h0[u] = 0.f, c0[u] = 0.f, h1[u] = 0.f, c1[u] = 0.f), ...);
        };
        zero(0, 1, 2, 3, 4, 5, 6, 7, 8, 9, 10, 11, 12, 13, 14, 15, 16, 17, 18, 19);
    }

    int wb = 0;  // laundered weight base: re-opaqued per timestep (kills LICM hoist)

    // ---- encoder over lookback T=8 (input = concat[y,x,u,s] = 16 feats) ----
#pragma clang loop unroll(disable)
    for (int t = 0; t < 8; ++t) {
        asm volatile("" : "+s"(wb));
        float x[16];
        x[0] = y_past[e * 8 + t];
        {
            const float4* p = (const float4*)(x_past + (size_t)(e * 8 + t) * 8);
            float4 a0 = p[0], a1 = p[1];
            x[1] = a0.x; x[2] = a0.y; x[3] = a0.z; x[4] = a0.w;
            x[5] = a1.x; x[6] = a1.y; x[7] = a1.z; x[8] = a1.w;
        }
        {
            const float4* p = (const float4*)(u_past + (size_t)(e * 8 + t) * 4);
            float4 a0 = p[0];
            x[9] = a0.x; x[10] = a0.y; x[11] = a0.z; x[12] = a0.w;
        }
        {
            const float* p = s_past + (size_t)(e * 8 + t) * 3;
            x[13] = p[0]; x[14] = p[1]; x[15] = p[2];
        }
        cell<W_Wih1_0, W_Whh1_0, W_b1_0, 16, BLK16>(smem, wb, s, m, mm1, x, h0, c0);
        cell<W_Wih1_1, W_Whh1_1, W_b1_1, HH, BLK20>(smem, wb, s, m, mm1, h0, h1, c1);
    }

    // ---- decoder over lookahead T=4 (input = u_future, 4 feats) + MLP head ----
#pragma clang loop unroll(disable)
    for (int t = 0; t < 4; ++t) {
        asm volatile("" : "+s"(wb));
        float x[4];
        {
            const float4* p = (const float4*)(u_future + (size_t)(e * 4 + t) * 4);
            float4 a0 = p[0];
            x[0] = a0.x; x[1] = a0.y; x[2] = a0.z; x[3] = a0.w;
        }
        cell<W_Wih2_0, W_Whh2_0, W_b2_0, 4, BLK4>(smem, wb, s, m, mm1, x, h0, c0);
        cell<W_Wih2_1, W_Whh2_1, W_b2_1, HH, BLK20>(smem, wb, s, m, mm1, h0, h1, c1);

        // FCNN 20 -> 10 -> 10 -> 1 on OWN element's h1 (no selection needed)
        float z1[10], z2[10];
        mlp_l1(smem, wb, h1, z1, std::make_index_sequence<10>{});
        mlp_l2(smem, wb, z1, z2, std::make_index_sequence<10>{});
        float o = mlp_dot<W_fW3, 0, 10>(smem, wb, z2, smem[wb + W_fb3],
                                        std::make_index_sequence<10>{});
        out[e * 4 + t] = o;
    }
}

extern "C" void kernel_launch(void* const* d_in, const int* in_sizes, int n_in,
                              void* d_out, int out_size, void* d_ws, size_t ws_size,
                              hipStream_t stream) {
    (void)n_in; (void)d_ws; (void)ws_size;
    const float* y_past   = (const float*)d_in[0];
    const float* x_past   = (const float*)d_in[1];
    const float* u_past   = (const float*)d_in[2];
    const float* s_past   = (const float*)d_in[3];
    const float* u_future = (const float*)d_in[4];
    const float* Wih1_0 = (const float*)d_in[5];
    const float* Whh1_0 = (const float*)d_in[6];
    const float* b1_0   = (const float*)d_in[7];
    const float* Wih1_1 = (const float*)d_in[8];
    const float* Whh1_1 = (const float*)d_in[9];
    const float* b1_1   = (const float*)d_in[10];
    const float* Wih2_0 = (const float*)d_in[11];
    const float* Whh2_0 = (const float*)d_in[12];
    const float* b2_0   = (const float*)d_in[13];
    const float* Wih2_1 = (const float*)d_in[14];
    const float* Whh2_1 = (const float*)d_in[15];
    const float* b2_1   = (const float*)d_in[16];
    const float* fW1 = (const float*)d_in[17];
    const float* fb1 = (const float*)d_in[18];
    const float* fW2 = (const float*)d_in[19];
    const float* fb2 = (const float*)d_in[20];
    const float* fW3 = (const float*)d_in[21];
    const float* fb3 = (const float*)d_in[22];
    float* out = (float*)d_out;

    int B = in_sizes[0] / 8;  // y_past is [B,8,1]
    (void)out_size;

    dim3 block(256);
    dim3 grid((B + 255) / 256);
    lstm_ar_kernel<<<grid, block, 0, stream>>>(
        y_past, x_past, u_past, s_past, u_future,
        Wih1_0, Whh1_0, b1_0, Wih1_1, Whh1_1, b1_1,
        Wih2_0, Whh2_0, b2_0, Wih2_1, Whh2_1, b2_1,
        fW1, fb1, fW2, fb2, fW3, fb3, out, B);
}

// Round 11
// 561.339 us; speedup vs baseline: 1.0434x; 1.0434x over previous
//
#include <hip/hip_runtime.h>
#include <utility>

#define HH 20

typedef float v2f __attribute__((ext_vector_type(2)));

// Raw v_rcp_f32 (~1 ulp); threshold 1.9e-3.
__device__ __forceinline__ float fast_rcp(float x) { return __builtin_amdgcn_rcpf(x); }
__device__ __forceinline__ float fsigmoid(float x) { return fast_rcp(1.0f + __expf(-x)); }
__device__ __forceinline__ float ftanh(float x) {
    float e = __expf(2.0f * x);
    return 1.0f - 2.0f * fast_rcp(e + 1.0f);
}
// DPP quad_perm [1,0,3,2]: swap values across adjacent lane pairs (VALU pipe).
__device__ __forceinline__ float pswap(float v) {
    return __int_as_float(__builtin_amdgcn_mov_dpp(__float_as_int(v), 0xB1, 0xF, 0xF, true));
}
// v_pk_fma_f32: two independent IEEE fp32 FMAs per instruction. Each half is
// bit-identical to the scalar fmaf chain it replaces.
__device__ __forceinline__ v2f fma2(v2f a, v2f b, v2f c) {
#if __has_builtin(__builtin_elementwise_fma)
    return __builtin_elementwise_fma(a, b, c);
#else
    v2f r; r.x = fmaf(a.x, b.x, c.x); r.y = fmaf(a.y, b.y, c.y); return r;
#endif
}

// ---- LDS weight arena with per-gate bank pads (R8-verified layout) ----------
// Each gate block is 20*IN + 4 floats: the wave's two concurrent row addresses
// (s=0: gates i/f, s=1: o/g) land on disjoint bank quads (R7's 1.05e7 conflict
// cycles -> R8's ~0).
constexpr int BLK16 = 20 * 16 + 4;   // 324
constexpr int BLK20 = 20 * 20 + 4;   // 404
constexpr int BLK4  = 20 * 4 + 4;    // 84

constexpr int W_Wih1_0 = 0;
constexpr int W_Whh1_0 = W_Wih1_0 + 4 * BLK16;    // 1296
constexpr int W_b1_0   = W_Whh1_0 + 4 * BLK20;    // 2912
constexpr int W_Wih1_1 = W_b1_0 + 80;             // 2992
constexpr int W_Whh1_1 = W_Wih1_1 + 4 * BLK20;    // 4608
constexpr int W_b1_1   = W_Whh1_1 + 4 * BLK20;    // 6224
constexpr int W_Wih2_0 = W_b1_1 + 80;             // 6304
constexpr int W_Whh2_0 = W_Wih2_0 + 4 * BLK4;     // 6640
constexpr int W_b2_0   = W_Whh2_0 + 4 * BLK20;    // 8256
constexpr int W_Wih2_1 = W_b2_0 + 80;             // 8336
constexpr int W_Whh2_1 = W_Wih2_1 + 4 * BLK20;    // 9952
constexpr int W_b2_1   = W_Whh2_1 + 4 * BLK20;    // 11568
constexpr int W_fW1    = W_b2_1 + 80;             // 11648
constexpr int W_fb1    = W_fW1 + 200;             // 11848
constexpr int W_fW2    = W_fb1 + 12;              // 11860
constexpr int W_fb2    = W_fW2 + 100;             // 11960
constexpr int W_fW3    = W_fb2 + 12;              // 11972
constexpr int W_fb3    = W_fW3 + 10;              // 11982
constexpr int LDS_TOT  = W_fb3 + 2;               // 11984 floats = 47.9 KB

// One float4 weight chunk: 4 pk-fma (= 8 scalar FMAs in R8). v[k] holds
// (own, oth) for input element k; weight splat hits both halves.
template <int IN, size_t U, size_t K>
__device__ __forceinline__ void row2_k(const float (&sm)[LDS_TOT], int rb,
                                       const v2f (&v)[IN], v2f& a) {
    float4 w = *(const float4*)&sm[rb + (int)(U * IN + 4 * K)];
    v2f w0 = {w.x, w.x}, w1 = {w.y, w.y}, w2 = {w.z, w.z}, w3 = {w.w, w.w};
    a = fma2(w0, v[4 * K + 0], a);
    a = fma2(w1, v[4 * K + 1], a);
    a = fma2(w2, v[4 * K + 2], a);
    a = fma2(w3, v[4 * K + 3], a);
}
template <int IN, size_t U, size_t... K>
__device__ __forceinline__ void row2(const float (&sm)[LDS_TOT], int rb,
                                     const v2f (&v)[IN], v2f& a, std::index_sequence<K...>) {
    (row2_k<IN, U, K>(sm, rb, v, a), ...);
}

// One LSTM unit, gate-split across a lane pair (R8 structure, pk-fma chains).
// s=0 lane: rows A=i, B=f (m=1 -> B act = sigma); s=1: A=o, B=g (m=2 -> tanh).
template <int IN, size_t U>
__device__ __forceinline__ void unit2(const float (&sm)[LDS_TOT], int s, float m, float mm1,
                                      int wihA, int wihB, int whhA, int whhB, int bA, int bB,
                                      const v2f (&xp)[IN], const v2f (&hp)[HH],
                                      float (&c_own)[HH], float (&hn)[HH]) {
    float bAv = sm[bA + (int)U];
    float bBv = sm[bB + (int)U];
    v2f aA = {bAv, bAv};
    v2f aB = {bBv, bBv};
    row2<IN, U>(sm, wihA, xp, aA, std::make_index_sequence<IN / 4>{});
    row2<IN, U>(sm, wihB, xp, aB, std::make_index_sequence<IN / 4>{});
    row2<HH, U>(sm, whhA, hp, aA, std::make_index_sequence<HH / 4>{});
    row2<HH, U>(sm, whhB, hp, aB, std::make_index_sequence<HH / 4>{});
    float Ao = fsigmoid(aA.x), At = fsigmoid(aA.y);
    float Bo = fmaf(m, fsigmoid(m * aB.x), -mm1);
    float Bt = fmaf(m, fsigmoid(m * aB.y), -mm1);
    float rA = pswap(At);   // s=0 receives sigma(o,own); s=1 receives sigma(i,own)
    float rB = pswap(Bt);   // s=0 receives tanh(g,own);  s=1 receives sigma(f,own)
    float sf = s ? rB : Bo;
    float si = s ? rA : Ao;
    float tg = s ? Bo : rB;
    float so = s ? Ao : rA;
    float cn = fmaf(sf, c_own[U], si * tg);
    c_own[U] = cn;
    hn[U] = so * ftanh(cn);
}

template <int WIH, int WHH, int BOFF, int IN, int BLK, size_t... U, size_t... K>
__device__ __forceinline__ void cell_impl(const float (&sm)[LDS_TOT], int wb, int s,
                                          float m, float mm1,
                                          const float (&x_own)[IN],
                                          float (&h_own)[HH], float (&c_own)[HH],
                                          std::index_sequence<U...>, std::index_sequence<K...>) {
    // (own, oth) pairs formed once per cell (DPP on the VALU pipe), reused by
    // all 20 units x 2 rows.
    v2f xp[IN], hp[HH];
    ((xp[K].x = x_own[K], xp[K].y = pswap(x_own[K])), ...);
    ((hp[U].x = h_own[U], hp[U].y = pswap(h_own[U])), ...);
    const int gA = s ? 3 : 0, gB = s ? 2 : 1;
    int wihA = wb + WIH + gA * BLK;
    int wihB = wb + WIH + gB * BLK;
    int whhA = wb + WHH + gA * BLK20;
    int whhB = wb + WHH + gB * BLK20;
    int bA = wb + BOFF + gA * 20;
    int bB = wb + BOFF + gB * 20;
    float hn[HH];
    (unit2<IN, U>(sm, s, m, mm1, wihA, wihB, whhA, whhB, bA, bB,
                  xp, hp, c_own, hn), ...);
    ((h_own[U] = hn[U]), ...);
}

template <int WIH, int WHH, int BOFF, int IN, int BLK>
__device__ __forceinline__ void cell(const float (&sm)[LDS_TOT], int wb, int s,
                                     float m, float mm1, const float (&x_own)[IN],
                                     float (&h_own)[HH], float (&c_own)[HH]) {
    cell_impl<WIH, WHH, BOFF, IN, BLK>(sm, wb, s, m, mm1, x_own, h_own, c_own,
                                       std::make_index_sequence<HH>{},
                                       std::make_index_sequence<IN>{});
}

// ---- MLP: R8-identical serial structure -------------------------------------
template <int WOFF, size_t J, int LD, int NV, size_t... K>
__device__ __forceinline__ float mlp_dot(const float (&sm)[LDS_TOT], int wb, const float (&v)[NV],
                                         float a, std::index_sequence<K...>) {
    ((a = fmaf(sm[wb + WOFF + (int)(J * LD + K)], v[K], a)), ...);
    return a;
}
template <size_t... J>
__device__ __forceinline__ void mlp_l1(const float (&sm)[LDS_TOT], int wb,
                                       const float (&h)[HH], float (&z)[10], std::index_sequence<J...>) {
    ((z[J] = fmaxf(mlp_dot<W_fW1, J, HH>(sm, wb, h, sm[wb + W_fb1 + (int)J],
                                         std::make_index_sequence<HH>{}), 0.f)), ...);
}
template <size_t... J>
__device__ __forceinline__ void mlp_l2(const float (&sm)[LDS_TOT], int wb,
                                       const float (&z1)[10], float (&z2)[10], std::index_sequence<J...>) {
    ((z2[J] = fmaxf(mlp_dot<W_fW2, J, 10>(sm, wb, z1, sm[wb + W_fb2 + (int)J],
                                          std::make_index_sequence<10>{}), 0.f)), ...);
}

__global__ void __launch_bounds__(256, 2) lstm_ar_kernel(
    const float* __restrict__ y_past, const float* __restrict__ x_past,
    const float* __restrict__ u_past, const float* __restrict__ s_past,
    const float* __restrict__ u_future,
    const float* __restrict__ Wih1_0, const float* __restrict__ Whh1_0, const float* __restrict__ b1_0,
    const float* __restrict__ Wih1_1, const float* __restrict__ Whh1_1, const float* __restrict__ b1_1,
    const float* __restrict__ Wih2_0, const float* __restrict__ Whh2_0, const float* __restrict__ b2_0,
    const float* __restrict__ Wih2_1, const float* __restrict__ Whh2_1, const float* __restrict__ b2_1,
    const float* __restrict__ fW1, const float* __restrict__ fb1,
    const float* __restrict__ fW2, const float* __restrict__ fb2,
    const float* __restrict__ fW3, const float* __restrict__ fb3,
    float* __restrict__ out, int B) {
    __shared__ __align__(16) float smem[LDS_TOT];
    const int tid = threadIdx.x;

    // ---- stage weights into LDS with per-gate +4 pads (R8-identical) ----
    auto stage_w = [&](const float* src, int off, int IN) {
        const int gb = 20 * IN;
        for (int i = tid; i < 4 * gb; i += 256) {
            int g = i / gb;
            smem[off + g * (gb + 4) + (i - g * gb)] = src[i];
        }
    };
    auto stage = [&](const float* src, int off, int n) {
        for (int i = tid; i < n; i += 256) smem[off + i] = src[i];
    };
    stage_w(Wih1_0, W_Wih1_0, 16);
    stage_w(Whh1_0, W_Whh1_0, 20);
    stage(b1_0, W_b1_0, 80);
    stage_w(Wih1_1, W_Wih1_1, 20);
    stage_w(Whh1_1, W_Whh1_1, 20);
    stage(b1_1, W_b1_1, 80);
    stage_w(Wih2_0, W_Wih2_0, 4);
    stage_w(Whh2_0, W_Whh2_0, 20);
    stage(b2_0, W_b2_0, 80);
    stage_w(Wih2_1, W_Wih2_1, 20);
    stage_w(Whh2_1, W_Whh2_1, 20);
    stage(b2_1, W_b2_1, 80);
    stage(fW1, W_fW1, 200);
    stage(fb1, W_fb1, 10);
    stage(fW2, W_fW2, 100);
    stage(fb2, W_fb2, 10);
    stage(fW3, W_fW3, 10);
    stage(fb3, W_fb3, 1);
    __syncthreads();

    const int s = tid & 1;                    // gate half: 0 -> (i,f), 1 -> (o,g)
    const int e = blockIdx.x * 256 + tid;     // OWN element == global thread id
    if (e >= B) return;                       // never taken (B % 256 == 0)

    const float m   = s ? 2.0f : 1.0f;
    const float mm1 = m - 1.0f;

    // own-element state only: 80 registers
    float h0[HH], c0[HH], h1[HH], c1[HH];
    {
        auto zero = [&](auto... u) {
            ((h0[u] = 0.f, c0[u] = 0.f, h1[u] = 0.f, c1[u] = 0.f), ...);
        };
        zero(0, 1, 2, 3, 4, 5, 6, 7, 8, 9, 10, 11, 12, 13, 14, 15, 16, 17, 18, 19);
    }

    int wb = 0;  // laundered weight base: re-opaqued per timestep (kills LICM hoist)

    // ---- encoder over lookback T=8 (input = concat[y,x,u,s] = 16 feats) ----
#pragma clang loop unroll(disable)
    for (int t = 0; t < 8; ++t) {
        asm volatile("" : "+s"(wb));
        float x[16];
        x[0] = y_past[e * 8 + t];
        {
            const float4* p = (const float4*)(x_past + (size_t)(e * 8 + t) * 8);
            float4 a0 = p[0], a1 = p[1];
            x[1] = a0.x; x[2] = a0.y; x[3] = a0.z; x[4] = a0.w;
            x[5] = a1.x; x[6] = a1.y; x[7] = a1.z; x[8] = a1.w;
        }
        {
            const float4* p = (const float4*)(u_past + (size_t)(e * 8 + t) * 4);
            float4 a0 = p[0];
            x[9] = a0.x; x[10] = a0.y; x[11] = a0.z; x[12] = a0.w;
        }
        {
            const float* p = s_past + (size_t)(e * 8 + t) * 3;
            x[13] = p[0]; x[14] = p[1]; x[15] = p[2];
        }
        cell<W_Wih1_0, W_Whh1_0, W_b1_0, 16, BLK16>(smem, wb, s, m, mm1, x, h0, c0);
        cell<W_Wih1_1, W_Whh1_1, W_b1_1, HH, BLK20>(smem, wb, s, m, mm1, h0, h1, c1);
    }

    // ---- decoder over lookahead T=4 (input = u_future, 4 feats) + MLP head ----
#pragma clang loop unroll(disable)
    for (int t = 0; t < 4; ++t) {
        asm volatile("" : "+s"(wb));
        float x[4];
        {
            const float4* p = (const float4*)(u_future + (size_t)(e * 4 + t) * 4);
            float4 a0 = p[0];
            x[0] = a0.x; x[1] = a0.y; x[2] = a0.z; x[3] = a0.w;
        }
        cell<W_Wih2_0, W_Whh2_0, W_b2_0, 4, BLK4>(smem, wb, s, m, mm1, x, h0, c0);
        cell<W_Wih2_1, W_Whh2_1, W_b2_1, HH, BLK20>(smem, wb, s, m, mm1, h0, h1, c1);

        // FCNN 20 -> 10 -> 10 -> 1 on OWN element's h1
        float z1[10], z2[10];
        mlp_l1(smem, wb, h1, z1, std::make_index_sequence<10>{});
        mlp_l2(smem, wb, z1, z2, std::make_index_sequence<10>{});
        float o = mlp_dot<W_fW3, 0, 10>(smem, wb, z2, smem[wb + W_fb3],
                                        std::make_index_sequence<10>{});
        out[e * 4 + t] = o;
    }
}

extern "C" void kernel_launch(void* const* d_in, const int* in_sizes, int n_in,
                              void* d_out, int out_size, void* d_ws, size_t ws_size,
                              hipStream_t stream) {
    (void)n_in; (void)d_ws; (void)ws_size;
    const float* y_past   = (const float*)d_in[0];
    const float* x_past   = (const float*)d_in[1];
    const float* u_past   = (const float*)d_in[2];
    const float* s_past   = (const float*)d_in[3];
    const float* u_future = (const float*)d_in[4];
    const float* Wih1_0 = (const float*)d_in[5];
    const float* Whh1_0 = (const float*)d_in[6];
    const float* b1_0   = (const float*)d_in[7];
    const float* Wih1_1 = (const float*)d_in[8];
    const float* Whh1_1 = (const float*)d_in[9];
    const float* b1_1   = (const float*)d_in[10];
    const float* Wih2_0 = (const float*)d_in[11];
    const float* Whh2_0 = (const float*)d_in[12];
    const float* b2_0   = (const float*)d_in[13];
    const float* Wih2_1 = (const float*)d_in[14];
    const float* Whh2_1 = (const float*)d_in[15];
    const float* b2_1   = (const float*)d_in[16];
    const float* fW1 = (const float*)d_in[17];
    const float* fb1 = (const float*)d_in[18];
    const float* fW2 = (const float*)d_in[19];
    const float* fb2 = (const float*)d_in[20];
    const float* fW3 = (const float*)d_in[21];
    const float* fb3 = (const float*)d_in[22];
    float* out = (float*)d_out;

    int B = in_sizes[0] / 8;  // y_past is [B,8,1]
    (void)out_size;

    dim3 block(256);
    dim3 grid((B + 255) / 256);
    lstm_ar_kernel<<<grid, block, 0, stream>>>(
        y_past, x_past, u_past, s_past, u_future,
        Wih1_0, Whh1_0, b1_0, Wih1_1, Whh1_1, b1_1,
        Wih2_0, Whh2_0, b2_0, Wih2_1, Whh2_1, b2_1,
        fW1, fb1, fW2, fb2, fW3, fb3, out, B);
}